// Round 1
// baseline (141.657 us; speedup 1.0000x reference)
//
#include <hip/hip_runtime.h>

// Problem constants (match reference setup_inputs)
#define BB   4
#define NN   100000
#define CC   128
#define RESO 128
#define PIX  (RESO * RESO)          // 16384 pixels per (b, plane)
#define PLANE_ELEMS (BB * PIX)      // 65536 floats per (plane[, slice])
#define NSLICE 4
#define CSL (CC / NSLICE)           // 32 channels per slice
#define WS_FINAL_OFF (3 * NSLICE * PLANE_ELEMS)   // float offset of collapsed planes

// ---------------------------------------------------------------------------
// Kernel 1: partial channel-collapse with fc_w.
//   partial[plane*NSLICE + slice][b*PIX + idx] = sum_{c in slice} w[c]*img[b][c][idx]
// float4 loads (16 B/lane — the 6.29 TB/s streaming pattern, m13).
// Channel slicing keeps the grid at 64 x 12 = 768 blocks (3 blocks/CU) despite
// 4 pixels/thread, so latency hiding doesn't collapse.
// ---------------------------------------------------------------------------
__global__ __launch_bounds__(256) void reduce_planes_k(
    const float* __restrict__ cxz, const float* __restrict__ cxy,
    const float* __restrict__ cyz, const float* __restrict__ fcw,
    float* __restrict__ ws)
{
    const int t     = threadIdx.x;
    const int py    = blockIdx.y;        // plane*NSLICE + slice, 0..11
    const int plane = py >> 2;
    const int c0    = (py & 3) * CSL;

    __shared__ float w[CSL];
    if (t < CSL) w[t] = fcw[c0 + t];
    __syncthreads();

    const float* __restrict__ img = (plane == 0) ? cxz : (plane == 1) ? cxy : cyz;

    const int gp4 = (blockIdx.x * 256 + t) * 4;   // global pixel (b*PIX+idx), %4==0
    const int b   = gp4 >> 14;                    // / PIX
    const int idx = gp4 & (PIX - 1);

    const float4* __restrict__ base =
        reinterpret_cast<const float4*>(img + ((size_t)(b * CC + c0)) * PIX + idx);

    float4 acc = make_float4(0.f, 0.f, 0.f, 0.f);
#pragma unroll 16
    for (int c = 0; c < CSL; ++c) {
        const float4 v  = base[c * (PIX / 4)];
        const float  wc = w[c];
        acc.x = fmaf(wc, v.x, acc.x);
        acc.y = fmaf(wc, v.y, acc.y);
        acc.z = fmaf(wc, v.z, acc.z);
        acc.w = fmaf(wc, v.w, acc.w);
    }
    *reinterpret_cast<float4*>(ws + (size_t)py * PLANE_ELEMS + gp4) = acc;
}

// ---------------------------------------------------------------------------
// Kernel 2: collapse the NSLICE partials -> ws_final[plane][b][pix].
// 3.1 MB read / 0.8 MB write, L2-resident; ~2-3 us.
// ---------------------------------------------------------------------------
__global__ __launch_bounds__(256) void collapse_k(float* __restrict__ ws)
{
    const int e4    = (blockIdx.x * 256 + threadIdx.x) * 4;  // over 3*PLANE_ELEMS
    const int plane = e4 >> 16;                              // / PLANE_ELEMS
    const int gp    = e4 & (PLANE_ELEMS - 1);

    const float4* __restrict__ part = reinterpret_cast<const float4*>(ws);
    float4 s = make_float4(0.f, 0.f, 0.f, 0.f);
#pragma unroll
    for (int sl = 0; sl < NSLICE; ++sl) {
        const float4 v = part[((plane * NSLICE + sl) * PLANE_ELEMS + gp) >> 2];
        s.x += v.x; s.y += v.y; s.z += v.z; s.w += v.w;
    }
    *reinterpret_cast<float4*>(ws + WS_FINAL_OFF + e4) = s;
}

// ---------------------------------------------------------------------------
// Kernel 3: per-point bilinear sample of the 3 collapsed planes + linear head.
// After the [0, 1-1e-5] clip, x <= 127*(1-1e-5) = 126.9987 -> x0 in [0,126],
// x1 = x0+1 <= 127: the int clamps of the previous version are dead code.
// ---------------------------------------------------------------------------
__device__ __forceinline__ float bilin(const float* __restrict__ pb,
                                       float a, float bc)
{
    const float INV = 1.0f / (1.0f + 0.1f + 1e-5f);   // 1/1.10001
    const float HI  = 1.0f - 1e-5f;

    const float u = fminf(fmaxf(fmaf(a,  INV, 0.5f), 0.0f), HI);
    const float v = fminf(fmaxf(fmaf(bc, INV, 0.5f), 0.0f), HI);

    const float x = u * (float)(RESO - 1);
    const float y = v * (float)(RESO - 1);
    const float xf = floorf(x), yf = floorf(y);
    const float wx = x - xf,    wy = y - yf;
    const int   x0 = (int)xf,   y0 = (int)yf;

    const float* __restrict__ r0 = pb + y0 * RESO + x0;
    const float* __restrict__ r1 = r0 + RESO;
    const float v00 = r0[0], v01 = r0[1];
    const float v10 = r1[0], v11 = r1[1];

    const float top = fmaf(wx, v01 - v00, v00);
    const float bot = fmaf(wx, v11 - v10, v10);
    return fmaf(wy, bot - top, top);
}

__global__ __launch_bounds__(256) void sample_k(
    const float* __restrict__ p, const float* __restrict__ ws,
    const float* __restrict__ fcw, const float* __restrict__ fcb,
    float* __restrict__ out)
{
    const int b  = blockIdx.y;              // batch index: no integer division
    const int n0 = blockIdx.x * 256;

    // Stage this block's 256x3 point coords through LDS with coalesced
    // dword loads (stride-3 direct loads waste ~3x transactions).
    __shared__ float sp[256 * 3];
    {
        const int cnt = min(256, NN - n0) * 3;
        const float* __restrict__ pb = p + (size_t)3 * ((size_t)b * NN + n0);
        for (int j = threadIdx.x; j < cnt; j += 256) sp[j] = pb[j];
    }
    __syncthreads();

    const int n = n0 + threadIdx.x;
    if (n >= NN) return;

    const float p0 = sp[3 * threadIdx.x + 0];
    const float p1 = sp[3 * threadIdx.x + 1];
    const float p2 = sp[3 * threadIdx.x + 2];

    const float* __restrict__ wsf = ws + WS_FINAL_OFF + (size_t)b * PIX;

    float s = bilin(wsf + 0 * PLANE_ELEMS, p0, p2)    // c_xz: (u=p0, v=p2)
            + bilin(wsf + 1 * PLANE_ELEMS, p0, p1)    // c_xy: (u=p0, v=p1)
            + bilin(wsf + 2 * PLANE_ELEMS, p1, p2);   // c_yz: (u=p1, v=p2)

    s = fmaf(p0, fcw[CC + 0], s);
    s = fmaf(p1, fcw[CC + 1], s);
    s = fmaf(p2, fcw[CC + 2], s);
    s += fcb[0];

    out[(size_t)b * NN + n] = s;
}

// ---------------------------------------------------------------------------
extern "C" void kernel_launch(void* const* d_in, const int* in_sizes, int n_in,
                              void* d_out, int out_size, void* d_ws, size_t ws_size,
                              hipStream_t stream) {
    const float* p   = (const float*)d_in[0];
    const float* cxz = (const float*)d_in[1];
    const float* cxy = (const float*)d_in[2];
    const float* cyz = (const float*)d_in[3];
    const float* fcw = (const float*)d_in[4];
    const float* fcb = (const float*)d_in[5];
    float* out = (float*)d_out;
    float* ws  = (float*)d_ws;   // uses (12+3)*65536*4 B ~= 3.9 MB

    // 64 x 12 = 768 blocks: float4 streaming of all 100.7 MB of plane data.
    dim3 g1(PLANE_ELEMS / (256 * 4), 3 * NSLICE);
    reduce_planes_k<<<g1, 256, 0, stream>>>(cxz, cxy, cyz, fcw, ws);

    // 192 blocks: sum the 4 channel-slice partials.
    collapse_k<<<(3 * PLANE_ELEMS / 4) / 256, 256, 0, stream>>>(ws);

    // 391 x 4 blocks: bilinear sample + head.
    dim3 g3((NN + 255) / 256, BB);
    sample_k<<<g3, 256, 0, stream>>>(p, ws, fcw, fcb, out);
}